// Round 11
// baseline (207.796 us; speedup 1.0000x reference)
//
#include <hip/hip_runtime.h>

#define D 128
#define BE 4096     // edges per sort block
#define SC 5120     // brec records per bucket (Poisson(4096), 16-sigma headroom)
#define LROW 136    // padded LDS row stride in ushorts (272 B)

typedef __attribute__((ext_vector_type(8))) short bf16x8;
typedef __attribute__((ext_vector_type(4))) float f32x4;
typedef __attribute__((ext_vector_type(8))) unsigned short u16x8;

// ---------- bf16 helpers (manual, RNE) ----------
__device__ inline unsigned short f2bf(float f) {
    unsigned u = __float_as_uint(f);
    return (unsigned short)((u + 0x7fff + ((u >> 16) & 1)) >> 16);
}
__device__ inline float bf2f(unsigned short s) {
    return __uint_as_float((unsigned)s << 16);
}
__device__ inline bf16x8 cvt8(const float* __restrict__ p) {
    float4 a = *(const float4*)p;
    float4 b = *(const float4*)(p + 4);
    bf16x8 r;
    r[0] = (short)f2bf(a.x); r[1] = (short)f2bf(a.y);
    r[2] = (short)f2bf(a.z); r[3] = (short)f2bf(a.w);
    r[4] = (short)f2bf(b.x); r[5] = (short)f2bf(b.y);
    r[6] = (short)f2bf(b.z); r[7] = (short)f2bf(b.w);
    return r;
}

// ---------- prep: W1,W2 fp32 -> bf16; zero bucket counters + global base ---
__global__ void k_prep(const float* __restrict__ W1, const float* __restrict__ W2,
                       unsigned short* __restrict__ Wb1, unsigned short* __restrict__ Wb2,
                       int* __restrict__ bcnt, int* __restrict__ gcnt, int NBK) {
    int i = blockIdx.x * 256 + threadIdx.x;
    if (i < D * D) { Wb1[i] = f2bf(W1[i]); Wb2[i] = f2bf(W2[i]); }
    if (i < NBK) bcnt[i] = 0;
    if (i == D * D) *gcnt = 0;
}

// ---------- zero-LDS MFMA gemm tile (128 nodes per block, 32 per wave) -----
// C = W · x^T with mfma_f32_16x16x32_bf16; fragments straight from global
// (Wb 64KB stays L2-hot). C layout (m89): col(lane&15)=node, row=(lane>>4)*4+reg.
// #pragma unroll 1 on ks-loop: round-3 lesson (full unroll -> hoist/spill).

__device__ inline void gemm_tile_f32in(const float* __restrict__ xx,
                                       const unsigned short* __restrict__ Wb,
                                       unsigned short* __restrict__ g,
                                       int N, int tile, int t) {
    int w = t >> 6, l = t & 63;
    int r16 = l & 15, g4 = l >> 4;
    int base = tile * 128 + w * 32;
    int row0 = base + r16, row1 = row0 + 16;
    int cr0 = (row0 < N) ? row0 : N - 1;
    int cr1 = (row1 < N) ? row1 : N - 1;

    f32x4 acc0[8] = {};
    f32x4 acc1[8] = {};
    const unsigned short* wr = Wb + r16 * D + g4 * 8;

#pragma unroll 1
    for (int ks = 0; ks < 4; ks++) {
        bf16x8 b0 = cvt8(xx + (size_t)cr0 * D + g4 * 8 + ks * 32);
        bf16x8 b1 = cvt8(xx + (size_t)cr1 * D + g4 * 8 + ks * 32);
#pragma unroll
        for (int jt = 0; jt < 8; jt++) {
            bf16x8 a = *(const bf16x8*)(wr + jt * 16 * D + ks * 32);
            acc0[jt] = __builtin_amdgcn_mfma_f32_16x16x32_bf16(a, b0, acc0[jt], 0, 0, 0);
            acc1[jt] = __builtin_amdgcn_mfma_f32_16x16x32_bf16(a, b1, acc1[jt], 0, 0, 0);
        }
    }
#pragma unroll
    for (int tt = 0; tt < 2; tt++) {
        int row = base + tt * 16 + r16;
        if (row < N) {
#pragma unroll
            for (int jt = 0; jt < 8; jt++) {
                f32x4 a = tt ? acc1[jt] : acc0[jt];
                ushort4 o = { f2bf(a[0]), f2bf(a[1]), f2bf(a[2]), f2bf(a[3]) };
                *(ushort4*)&g[(size_t)row * D + jt * 16 + g4 * 4] = o;
            }
        }
    }
}

// ---------- fused K1: edge counting-sort (1/5 of blocks) || gemm1 (4/5) ----
// Sort: 4096 edges -> LDS counting sort by bucket dst>>9, reserve global
// ranges with 196 atomics, stream out coalesced. Record=(src<<9)|(dst&511).
// NOTE: harness delivers integer inputs as int32 (edge_index arrives as int*).

__global__ __launch_bounds__(256) void k_sort_gemm1(
        const int* __restrict__ ei, int* __restrict__ bcnt, unsigned* __restrict__ brec,
        const float* __restrict__ x, const unsigned short* __restrict__ Wb1,
        unsigned short* __restrict__ g, int N, int E, int ntiles, int fb, int NBK) {
    int bid = blockIdx.x;
    if (bid % 5 == 4) {                         // ---- sort role ----
        __shared__ unsigned srt[BE];            // 16 KB
        __shared__ unsigned char bko[BE];       // 4 KB
        __shared__ int hist[256];
        __shared__ int pfx[256];
        __shared__ int gbase[256];
        __shared__ int cur[256];
        int f = bid / 5;
        if (f >= fb) return;
        int t = threadIdx.x;
        int e0 = f * BE;
        int n = E - e0; if (n > BE) n = BE;

        hist[t] = 0; cur[t] = 0;
        __syncthreads();

        unsigned rec[16]; int mb[16];
#pragma unroll
        for (int j = 0; j < 16; j++) {
            int e = e0 + j * 256 + t;           // coalesced
            if (e < E) {
                int s = ei[e], d = ei[E + e];
                rec[j] = ((unsigned)s << 9) | (unsigned)(d & 511);
                mb[j] = d >> 9;
                atomicAdd(&hist[mb[j]], 1);
            } else mb[j] = -1;
        }
        __syncthreads();
        int v = hist[t];
        pfx[t] = v;
        __syncthreads();
        for (int dd = 1; dd < 256; dd <<= 1) {
            int xv = (t >= dd) ? pfx[t - dd] : 0;
            __syncthreads();
            pfx[t] += xv;
            __syncthreads();
        }
        pfx[t] -= v;                            // exclusive prefix
        if (v > 0 && t < NBK) gbase[t] = atomicAdd(&bcnt[t], v);
        __syncthreads();
#pragma unroll
        for (int j = 0; j < 16; j++) {
            if (mb[j] >= 0) {
                int p = pfx[mb[j]] + atomicAdd(&cur[mb[j]], 1);
                srt[p] = rec[j];
                bko[p] = (unsigned char)mb[j];
            }
        }
        __syncthreads();
        for (int i = t; i < n; i += 256) {      // bucket-ordered -> coalesced
            int b = bko[i];
            int pos = gbase[b] + (i - pfx[b]);
            if (pos < SC) brec[(size_t)b * SC + pos] = srt[i];
        }
    } else {                                    // ---- gemm1 role ----
        int gid = (bid / 5) * 4 + (bid % 5);
        if (gid >= ntiles) return;
        gemm_tile_f32in(x, Wb1, g, N, gid, threadIdx.x);
    }
}

// ---------- build: one block per bucket -> dense CSR (col, row_ptr, cnt) ---
// Pass 1 counts 512 local degrees; LDS scan + one global atomicAdd reserves
// a contiguous col range per bucket; pass 2 scatters into it (16KB window,
// L2-merged). col is exactly E ints.

__global__ __launch_bounds__(256) void k_build(const int* __restrict__ bcnt,
                                               const unsigned* __restrict__ brec,
                                               int* __restrict__ cnt,
                                               int* __restrict__ rp,
                                               int* __restrict__ col,
                                               int* __restrict__ gcnt, int N) {
    __shared__ int c512[512];
    __shared__ int base512[512];
    __shared__ int psc[256];
    __shared__ int bksum;
    int b = blockIdx.x, t = threadIdx.x;
    c512[t] = 0; c512[t + 256] = 0;
    __syncthreads();
    int total = bcnt[b]; if (total > SC) total = SC;
    for (int i = t; i < total; i += 256)
        atomicAdd(&c512[brec[(size_t)b * SC + i] & 511], 1);
    __syncthreads();
    int d0 = c512[2 * t], d1 = c512[2 * t + 1];
    int pair = d0 + d1;
    psc[t] = pair;
    __syncthreads();
    for (int dd = 1; dd < 256; dd <<= 1) {
        int xv = (t >= dd) ? psc[t - dd] : 0;
        __syncthreads();
        psc[t] += xv;
        __syncthreads();
    }
    int pexc = psc[t] - pair;
    if (t == 255) bksum = atomicAdd(gcnt, psc[255]);
    __syncthreads();
    int gb = bksum;
    base512[2 * t]     = gb + pexc;
    base512[2 * t + 1] = gb + pexc + d0;
    c512[2 * t] = 0; c512[2 * t + 1] = 0;
    __syncthreads();
    for (int i = t; i < total; i += 256) {
        unsigned rec = brec[(size_t)b * SC + i];
        int dl = rec & 511;
        int p = atomicAdd(&c512[dl], 1);
        col[base512[dl] + p] = (int)(rec >> 9);
    }
    __syncthreads();
#pragma unroll
    for (int k = 0; k < 2; k++) {
        int dl = t + k * 256;
        int node = b * 512 + dl;
        if (node < N) { cnt[node] = c512[dl]; rp[node] = base512[dl]; }
    }
}

// ---------- fused: agg1 (h tile in LDS) + gemm2 (MFMA) -> g2 ---------------
// Per 128-node tile: 16-lane groups aggregate h rows (bf16 gather of raw g,
// per-edge dis_u = rsqrt(cnt[u]+1), self term, bias+ReLU) straight into LDS;
// one barrier; MFMA phase consumes LDS rows as B-frags with W2 from L2, and
// folds dis_v into the g2 epilogue. Saves the 51MB h HBM round-trip.

__global__ __launch_bounds__(256) void k_agg1_gemm2(
        const unsigned short* __restrict__ g, const int* __restrict__ cnt,
        const int* __restrict__ rp, const int* __restrict__ col,
        const float* __restrict__ b1, const unsigned short* __restrict__ Wb2,
        unsigned short* __restrict__ g2, int N, int ntiles) {
    __shared__ __align__(16) unsigned short hl[128 * LROW];   // 34.8 KB
    int tile = blockIdx.x;
    if (tile >= ntiles) return;
    int t = threadIdx.x, grp = t >> 4, l16 = t & 15;
    const u16x8* G = (const u16x8*)g;
    const float4* B4 = (const float4*)b1;
    float4 bb0 = B4[l16 * 2], bb1 = B4[l16 * 2 + 1];

    // ---- agg phase: 16 groups x 8 nodes ----
#pragma unroll 1
    for (int ii = 0; ii < 8; ii++) {
        int local = grp * 8 + ii;
        int node = tile * 128 + local;
        u16x8 hv = {};
        if (node < N) {
            int deg = cnt[node];
            float disv = rsqrtf((float)(deg + 1));
            float acc[8];
            u16x8 s = G[(size_t)node * 16 + l16];     // self term (×disv)
#pragma unroll
            for (int j = 0; j < 8; j++) acc[j] = bf2f(s[j]) * disv;
            const int* cb = col + rp[node];
            int i = 0;
            for (; i + 7 < deg; i += 8) {
                int u[8]; u16x8 m[8]; float dd[8];
#pragma unroll
                for (int k = 0; k < 8; k++) u[k] = cb[i + k];
#pragma unroll
                for (int k = 0; k < 8; k++) m[k] = G[(size_t)u[k] * 16 + l16];
#pragma unroll
                for (int k = 0; k < 8; k++) dd[k] = rsqrtf((float)(cnt[u[k]] + 1));
#pragma unroll
                for (int j = 0; j < 8; j++) {
                    float s0 = fmaf(bf2f(m[0][j]), dd[0], bf2f(m[1][j]) * dd[1]);
                    float s1 = fmaf(bf2f(m[2][j]), dd[2], bf2f(m[3][j]) * dd[3]);
                    float s2 = fmaf(bf2f(m[4][j]), dd[4], bf2f(m[5][j]) * dd[5]);
                    float s3 = fmaf(bf2f(m[6][j]), dd[6], bf2f(m[7][j]) * dd[7]);
                    acc[j] += (s0 + s1) + (s2 + s3);
                }
            }
            for (; i < deg; i++) {
                int u = cb[i];
                u16x8 m = G[(size_t)u * 16 + l16];
                float du = rsqrtf((float)(cnt[u] + 1));
#pragma unroll
                for (int j = 0; j < 8; j++) acc[j] += bf2f(m[j]) * du;
            }
            float r[8];
            r[0] = fmaf(acc[0], disv, bb0.x); r[1] = fmaf(acc[1], disv, bb0.y);
            r[2] = fmaf(acc[2], disv, bb0.z); r[3] = fmaf(acc[3], disv, bb0.w);
            r[4] = fmaf(acc[4], disv, bb1.x); r[5] = fmaf(acc[5], disv, bb1.y);
            r[6] = fmaf(acc[6], disv, bb1.z); r[7] = fmaf(acc[7], disv, bb1.w);
#pragma unroll
            for (int j = 0; j < 8; j++) hv[j] = f2bf(fmaxf(r[j], 0.f));
        }
        *(u16x8*)&hl[local * LROW + l16 * 8] = hv;
    }
    __syncthreads();

    // ---- mfma phase: B-frags from LDS h tile, A-frags = W2 (L2-hot) ----
    int w = t >> 6, l = t & 63;
    int r16 = l & 15, g4 = l >> 4;
    int base = tile * 128 + w * 32;
    f32x4 acc0[8] = {};
    f32x4 acc1[8] = {};
    const unsigned short* wr = Wb2 + r16 * D + g4 * 8;
    int xb0 = (w * 32 + r16) * LROW + g4 * 8;
    int xb1 = xb0 + 16 * LROW;
#pragma unroll 1
    for (int ks = 0; ks < 4; ks++) {
        bf16x8 b0 = *(const bf16x8*)&hl[xb0 + ks * 32];
        bf16x8 b1v = *(const bf16x8*)&hl[xb1 + ks * 32];
#pragma unroll
        for (int jt = 0; jt < 8; jt++) {
            bf16x8 a = *(const bf16x8*)(wr + jt * 16 * D + ks * 32);
            acc0[jt] = __builtin_amdgcn_mfma_f32_16x16x32_bf16(a, b0, acc0[jt], 0, 0, 0);
            acc1[jt] = __builtin_amdgcn_mfma_f32_16x16x32_bf16(a, b1v, acc1[jt], 0, 0, 0);
        }
    }
#pragma unroll
    for (int tt = 0; tt < 2; tt++) {
        int row = base + tt * 16 + r16;
        if (row < N) {
            float dv = rsqrtf((float)(cnt[row] + 1));
#pragma unroll
            for (int jt = 0; jt < 8; jt++) {
                f32x4 a = tt ? acc1[jt] : acc0[jt];
                ushort4 o = { f2bf(a[0] * dv), f2bf(a[1] * dv),
                              f2bf(a[2] * dv), f2bf(a[3] * dv) };
                *(ushort4*)&g2[(size_t)row * D + jt * 16 + g4 * 4] = o;
            }
        }
    }
}

// ---------- agg2: final aggregation -> fp32 out ----------
// quarter-wave per node, 8 gathers in flight; g2 already dis-folded.

__global__ __launch_bounds__(256) void k_agg2(
        const unsigned short* __restrict__ g2, const int* __restrict__ cnt,
        const int* __restrict__ rp, const int* __restrict__ col,
        const float* __restrict__ b2, float* __restrict__ out, int N) {
    int node = blockIdx.x * 16 + (threadIdx.x >> 4);
    if (node >= N) return;
    int l16 = threadIdx.x & 15;
    const u16x8* G = (const u16x8*)g2;
    float acc[8];
    {
        u16x8 s = G[(size_t)node * 16 + l16];
#pragma unroll
        for (int j = 0; j < 8; j++) acc[j] = bf2f(s[j]);
    }
    int deg = cnt[node];
    const int* cb = col + rp[node];
    int i = 0;
    for (; i + 7 < deg; i += 8) {
        int u[8]; u16x8 m[8];
#pragma unroll
        for (int k = 0; k < 8; k++) u[k] = cb[i + k];
#pragma unroll
        for (int k = 0; k < 8; k++) m[k] = G[(size_t)u[k] * 16 + l16];
#pragma unroll
        for (int j = 0; j < 8; j++) {
            float s0 = (bf2f(m[0][j]) + bf2f(m[1][j])) + (bf2f(m[2][j]) + bf2f(m[3][j]));
            float s1 = (bf2f(m[4][j]) + bf2f(m[5][j])) + (bf2f(m[6][j]) + bf2f(m[7][j]));
            acc[j] += s0 + s1;
        }
    }
    for (; i + 3 < deg; i += 4) {
        int u0 = cb[i], u1 = cb[i + 1], u2 = cb[i + 2], u3 = cb[i + 3];
        u16x8 m0 = G[(size_t)u0 * 16 + l16];
        u16x8 m1 = G[(size_t)u1 * 16 + l16];
        u16x8 m2 = G[(size_t)u2 * 16 + l16];
        u16x8 m3 = G[(size_t)u3 * 16 + l16];
#pragma unroll
        for (int j = 0; j < 8; j++)
            acc[j] += (bf2f(m0[j]) + bf2f(m1[j])) + (bf2f(m2[j]) + bf2f(m3[j]));
    }
    for (; i < deg; i++) {
        u16x8 m = G[(size_t)cb[i] * 16 + l16];
#pragma unroll
        for (int j = 0; j < 8; j++) acc[j] += bf2f(m[j]);
    }
    float disv = rsqrtf((float)(deg + 1));
    const float4* B4 = (const float4*)b2;
    float4 bb0 = B4[l16 * 2], bb1 = B4[l16 * 2 + 1];
    float4 o0, o1;
    o0.x = fmaf(acc[0], disv, bb0.x); o0.y = fmaf(acc[1], disv, bb0.y);
    o0.z = fmaf(acc[2], disv, bb0.z); o0.w = fmaf(acc[3], disv, bb0.w);
    o1.x = fmaf(acc[4], disv, bb1.x); o1.y = fmaf(acc[5], disv, bb1.y);
    o1.z = fmaf(acc[6], disv, bb1.z); o1.w = fmaf(acc[7], disv, bb1.w);
    ((float4*)out)[(size_t)node * 32 + l16 * 2]     = o0;
    ((float4*)out)[(size_t)node * 32 + l16 * 2 + 1] = o1;
}

// ---------- launch ----------

extern "C" void kernel_launch(void* const* d_in, const int* in_sizes, int n_in,
                              void* d_out, int out_size, void* d_ws, size_t ws_size,
                              hipStream_t stream) {
    const float* x  = (const float*)d_in[0];
    const int*   ei = (const int*)d_in[1];
    const float* W1 = (const float*)d_in[2];
    const float* b1 = (const float*)d_in[3];
    const float* W2 = (const float*)d_in[4];
    const float* b2 = (const float*)d_in[5];
    float* out = (float*)d_out;

    int N = in_sizes[0] / D;
    int E = in_sizes[1] / 2;
    int NBK = (N + 511) >> 9;                // buckets of 512 nodes

    // ws: g 25.6 | g2 25.6 | cnt .4 | rp .4 | col E*4=3.2 | Wb .13
    //   | bcnt ~1KB | gcnt | brec 4  -> ~59.4 MB
    char* w = (char*)d_ws;
    unsigned short* g  = (unsigned short*)w;  size_t off = (size_t)N * D * 2;
    off = (off + 255) & ~(size_t)255;
    unsigned short* g2 = (unsigned short*)(w + off); off += (size_t)N * D * 2;
    off = (off + 255) & ~(size_t)255;
    int* cnt  = (int*)(w + off);             off += (size_t)N * 4;
    off = (off + 255) & ~(size_t)255;
    int* rp   = (int*)(w + off);             off += (size_t)N * 4;
    off = (off + 255) & ~(size_t)255;
    int* col  = (int*)(w + off);             off += (size_t)E * 4;
    off = (off + 255) & ~(size_t)255;
    unsigned short* Wb1 = (unsigned short*)(w + off); off += (size_t)D * D * 2;
    unsigned short* Wb2 = (unsigned short*)(w + off); off += (size_t)D * D * 2;
    off = (off + 255) & ~(size_t)255;
    int* bcnt = (int*)(w + off);             off += (size_t)NBK * 4;
    off = (off + 255) & ~(size_t)255;
    int* gcnt = (int*)(w + off);             off += 256;
    unsigned* brec = (unsigned*)(w + off);   off += (size_t)NBK * SC * 4;

    int ntiles = (N + 127) / 128;
    int fillB  = (E + BE - 1) / BE;
    int fb = fillB > (ntiles + 3) / 4 ? fillB : (ntiles + 3) / 4;
    int total  = 5 * fb;

    k_prep<<<(D * D + 511) / 256, 256, 0, stream>>>(W1, W2, Wb1, Wb2, bcnt, gcnt, NBK);

    // K1: counting-sort (ei -> bcnt,brec)  ||  gemm1 (g = bf16(x @ W1^T), raw)
    k_sort_gemm1<<<total, 256, 0, stream>>>(ei, bcnt, brec, x, Wb1, g, N, E,
                                            ntiles, fillB, NBK);
    // build: brec -> dense CSR (col, rp, cnt)
    k_build<<<NBK, 256, 0, stream>>>(bcnt, brec, cnt, rp, col, gcnt, N);

    // fused: h tile in LDS = relu(dis*(Σ g*dis_u + g_v*dis_v)+b1); g2 = bf16((h@W2^T)*dis)
    k_agg1_gemm2<<<ntiles, 256, 0, stream>>>(g, cnt, rp, col, b1, Wb2, g2, N, ntiles);

    // agg2: out = dis_v*(Σ g2[u] + g2[v]) + b2  (fp32)
    k_agg2<<<(N + 15) / 16, 256, 0, stream>>>(g2, cnt, rp, col, b2, out, N);
}

// Round 12
// 174.208 us; speedup vs baseline: 1.1928x; 1.1928x over previous
//
#include <hip/hip_runtime.h>

#define D 128
#define BE 4096     // edges per sort block
#define SC 5120     // brec records per bucket (Poisson(4096), 16-sigma headroom)

typedef __attribute__((ext_vector_type(8))) short bf16x8;
typedef __attribute__((ext_vector_type(4))) float f32x4;
typedef __attribute__((ext_vector_type(8))) unsigned short u16x8;

// ---------- bf16 helpers (manual, RNE) ----------
__device__ inline unsigned short f2bf(float f) {
    unsigned u = __float_as_uint(f);
    return (unsigned short)((u + 0x7fff + ((u >> 16) & 1)) >> 16);
}
__device__ inline float bf2f(unsigned short s) {
    return __uint_as_float((unsigned)s << 16);
}
__device__ inline bf16x8 cvt8(const float* __restrict__ p) {
    float4 a = *(const float4*)p;
    float4 b = *(const float4*)(p + 4);
    bf16x8 r;
    r[0] = (short)f2bf(a.x); r[1] = (short)f2bf(a.y);
    r[2] = (short)f2bf(a.z); r[3] = (short)f2bf(a.w);
    r[4] = (short)f2bf(b.x); r[5] = (short)f2bf(b.y);
    r[6] = (short)f2bf(b.z); r[7] = (short)f2bf(b.w);
    return r;
}

// ---------- prep: W1,W2 fp32 -> bf16; zero bucket counters + global base ---
__global__ void k_prep(const float* __restrict__ W1, const float* __restrict__ W2,
                       unsigned short* __restrict__ Wb1, unsigned short* __restrict__ Wb2,
                       int* __restrict__ bcnt, int* __restrict__ gcnt, int NBK) {
    int i = blockIdx.x * 256 + threadIdx.x;
    if (i < D * D) { Wb1[i] = f2bf(W1[i]); Wb2[i] = f2bf(W2[i]); }
    if (i < NBK) bcnt[i] = 0;
    if (i == D * D) *gcnt = 0;
}

// ---------- zero-LDS MFMA gemm tile (128 nodes per block, 32 per wave) -----
// C = W · x^T with mfma_f32_16x16x32_bf16; fragments straight from global
// (Wb 64KB stays L2-hot). C layout (m89): col(lane&15)=node, row=(lane>>4)*4+reg.
// #pragma unroll 1 on ks-loop: round-3 lesson (full unroll -> hoist/spill).

template <bool INBF16, bool FOLD>
__device__ inline void gemm_tile(const void* __restrict__ in_v,
                                 const unsigned short* __restrict__ Wb,
                                 const int* __restrict__ cnt,
                                 unsigned short* __restrict__ g,
                                 int N, int tile, int t) {
    int w = t >> 6, l = t & 63;
    int r16 = l & 15, g4 = l >> 4;
    int base = tile * 128 + w * 32;
    int row0 = base + r16, row1 = row0 + 16;
    int cr0 = (row0 < N) ? row0 : N - 1;
    int cr1 = (row1 < N) ? row1 : N - 1;

    f32x4 acc0[8] = {};
    f32x4 acc1[8] = {};
    const unsigned short* wr = Wb + r16 * D + g4 * 8;

#pragma unroll 1
    for (int ks = 0; ks < 4; ks++) {
        bf16x8 b0, b1;
        if (INBF16) {
            const unsigned short* h = (const unsigned short*)in_v;
            b0 = *(const bf16x8*)(h + (size_t)cr0 * D + g4 * 8 + ks * 32);
            b1 = *(const bf16x8*)(h + (size_t)cr1 * D + g4 * 8 + ks * 32);
        } else {
            const float* xx = (const float*)in_v;
            b0 = cvt8(xx + (size_t)cr0 * D + g4 * 8 + ks * 32);
            b1 = cvt8(xx + (size_t)cr1 * D + g4 * 8 + ks * 32);
        }
#pragma unroll
        for (int jt = 0; jt < 8; jt++) {
            bf16x8 a = *(const bf16x8*)(wr + jt * 16 * D + ks * 32);
            acc0[jt] = __builtin_amdgcn_mfma_f32_16x16x32_bf16(a, b0, acc0[jt], 0, 0, 0);
            acc1[jt] = __builtin_amdgcn_mfma_f32_16x16x32_bf16(a, b1, acc1[jt], 0, 0, 0);
        }
    }
#pragma unroll
    for (int tt = 0; tt < 2; tt++) {
        int row = base + tt * 16 + r16;
        if (row < N) {
            float dv = 1.0f;
            if (FOLD) dv = rsqrtf((float)(cnt[row] + 1));
#pragma unroll
            for (int jt = 0; jt < 8; jt++) {
                f32x4 a = tt ? acc1[jt] : acc0[jt];
                ushort4 o = { f2bf(a[0] * dv), f2bf(a[1] * dv),
                              f2bf(a[2] * dv), f2bf(a[3] * dv) };
                *(ushort4*)&g[(size_t)row * D + jt * 16 + g4 * 4] = o;
            }
        }
    }
}

// ---------- fused K1: edge counting-sort (1/5 of blocks) || gemm1 (4/5) ----
// Sort: 4096 edges -> LDS counting sort by bucket dst>>9, reserve global
// ranges with 196 atomics, stream out coalesced. Record=(src<<9)|(dst&511).
// NOTE: harness delivers integer inputs as int32 (edge_index arrives as int*).

__global__ __launch_bounds__(256) void k_sort_gemm1(
        const int* __restrict__ ei, int* __restrict__ bcnt, unsigned* __restrict__ brec,
        const float* __restrict__ x, const unsigned short* __restrict__ Wb1,
        unsigned short* __restrict__ g, int N, int E, int ntiles, int fb, int NBK) {
    int bid = blockIdx.x;
    if (bid % 5 == 4) {                         // ---- sort role ----
        __shared__ unsigned srt[BE];            // 16 KB
        __shared__ unsigned char bko[BE];       // 4 KB
        __shared__ int hist[256];
        __shared__ int pfx[256];
        __shared__ int gbase[256];
        __shared__ int cur[256];
        int f = bid / 5;
        if (f >= fb) return;
        int t = threadIdx.x;
        int e0 = f * BE;
        int n = E - e0; if (n > BE) n = BE;

        hist[t] = 0; cur[t] = 0;
        __syncthreads();

        unsigned rec[16]; int mb[16];
#pragma unroll
        for (int j = 0; j < 16; j++) {
            int e = e0 + j * 256 + t;           // coalesced
            if (e < E) {
                int s = ei[e], d = ei[E + e];
                rec[j] = ((unsigned)s << 9) | (unsigned)(d & 511);
                mb[j] = d >> 9;
                atomicAdd(&hist[mb[j]], 1);
            } else mb[j] = -1;
        }
        __syncthreads();
        int v = hist[t];
        pfx[t] = v;
        __syncthreads();
        for (int dd = 1; dd < 256; dd <<= 1) {
            int xv = (t >= dd) ? pfx[t - dd] : 0;
            __syncthreads();
            pfx[t] += xv;
            __syncthreads();
        }
        pfx[t] -= v;                            // exclusive prefix
        if (v > 0 && t < NBK) gbase[t] = atomicAdd(&bcnt[t], v);
        __syncthreads();
#pragma unroll
        for (int j = 0; j < 16; j++) {
            if (mb[j] >= 0) {
                int p = pfx[mb[j]] + atomicAdd(&cur[mb[j]], 1);
                srt[p] = rec[j];
                bko[p] = (unsigned char)mb[j];
            }
        }
        __syncthreads();
        for (int i = t; i < n; i += 256) {      // bucket-ordered -> coalesced
            int b = bko[i];
            int pos = gbase[b] + (i - pfx[b]);
            if (pos < SC) brec[(size_t)b * SC + pos] = srt[i];
        }
    } else {                                    // ---- gemm1 role ----
        int gid = (bid / 5) * 4 + (bid % 5);
        if (gid >= ntiles) return;
        gemm_tile<false, false>(x, Wb1, nullptr, g, N, gid, threadIdx.x);
    }
}

// ---------- build: one block per bucket -> dense CSR (col, row_ptr, cnt) ---
__global__ __launch_bounds__(256) void k_build(const int* __restrict__ bcnt,
                                               const unsigned* __restrict__ brec,
                                               int* __restrict__ cnt,
                                               int* __restrict__ rp,
                                               int* __restrict__ col,
                                               int* __restrict__ gcnt, int N) {
    __shared__ int c512[512];
    __shared__ int base512[512];
    __shared__ int psc[256];
    __shared__ int bksum;
    int b = blockIdx.x, t = threadIdx.x;
    c512[t] = 0; c512[t + 256] = 0;
    __syncthreads();
    int total = bcnt[b]; if (total > SC) total = SC;
    for (int i = t; i < total; i += 256)
        atomicAdd(&c512[brec[(size_t)b * SC + i] & 511], 1);
    __syncthreads();
    int d0 = c512[2 * t], d1 = c512[2 * t + 1];
    int pair = d0 + d1;
    psc[t] = pair;
    __syncthreads();
    for (int dd = 1; dd < 256; dd <<= 1) {
        int xv = (t >= dd) ? psc[t - dd] : 0;
        __syncthreads();
        psc[t] += xv;
        __syncthreads();
    }
    int pexc = psc[t] - pair;
    if (t == 255) bksum = atomicAdd(gcnt, psc[255]);
    __syncthreads();
    int gb = bksum;
    base512[2 * t]     = gb + pexc;
    base512[2 * t + 1] = gb + pexc + d0;
    c512[2 * t] = 0; c512[2 * t + 1] = 0;
    __syncthreads();
    for (int i = t; i < total; i += 256) {
        unsigned rec = brec[(size_t)b * SC + i];
        int dl = rec & 511;
        int p = atomicAdd(&c512[dl], 1);
        col[base512[dl] + p] = (int)(rec >> 9);
    }
    __syncthreads();
#pragma unroll
    for (int k = 0; k < 2; k++) {
        int dl = t + k * 256;
        int node = b * 512 + dl;
        if (node < N) { cnt[node] = c512[dl]; rp[node] = base512[dl]; }
    }
}

// ---------- standalone gemm2 (bf16 in, dis-folded out) ----------
__global__ __launch_bounds__(256) void k_gemm2(
        const unsigned short* __restrict__ h, const unsigned short* __restrict__ Wb2,
        const int* __restrict__ cnt, unsigned short* __restrict__ g2, int N, int ntiles) {
    if ((int)blockIdx.x >= ntiles) return;
    gemm_tile<true, true>(h, Wb2, cnt, g2, N, blockIdx.x, threadIdx.x);
}

// ---------- sparse aggregation: 2 nodes per 16-lane group ----------
// 8 gathers in flight per thread (4 per node), vs 4 in round 10 — doubles
// per-wave MLP at same occupancy (round-11 lesson: gathers need concurrency,
// never couple them to a compute tile). bf16 gather, fp32 accum.
// DISU (layer 1): per-edge dis_u = rsqrt(cnt[u]+1) since g is raw.

template <bool RELU, bool OUT_BF16, bool DISU>
__global__ __launch_bounds__(256) void k_agg(
        const unsigned short* __restrict__ gtab, const int* __restrict__ cnt,
        const int* __restrict__ rp, const int* __restrict__ col,
        const float* __restrict__ bias, void* __restrict__ out, int N) {
    int grp = threadIdx.x >> 4, l16 = threadIdx.x & 15;
    int n0 = (blockIdx.x * 16 + grp) * 2;
    if (n0 >= N) return;
    int n1 = n0 + 1;
    bool has1 = (n1 < N);
    const u16x8* G = (const u16x8*)gtab;

    int d0 = cnt[n0];
    int d1 = has1 ? cnt[n1] : 0;
    float dv0 = rsqrtf((float)(d0 + 1));
    float dv1 = rsqrtf((float)(d1 + 1));
    const int* cb0 = col + rp[n0];
    const int* cb1 = col + (has1 ? rp[n1] : rp[n0]);

    float acc0[8], acc1[8];
    {
        u16x8 s0 = G[(size_t)n0 * 16 + l16];
        u16x8 s1 = G[(size_t)(has1 ? n1 : n0) * 16 + l16];
        float f0 = DISU ? dv0 : 1.0f, f1 = DISU ? dv1 : 1.0f;
#pragma unroll
        for (int j = 0; j < 8; j++) {
            acc0[j] = bf2f(s0[j]) * f0;
            acc1[j] = bf2f(s1[j]) * f1;
        }
    }
    if (!has1) {
#pragma unroll
        for (int j = 0; j < 8; j++) acc1[j] = 0.f;
    }

    int dm = d0 > d1 ? d0 : d1;
    int i = 0;
    for (; i + 3 < dm; i += 4) {
        int u0[4], u1[4]; float w0[4], w1[4];
#pragma unroll
        for (int k = 0; k < 4; k++) {
            bool v0 = (i + k < d0), v1 = (i + k < d1);
            u0[k] = v0 ? cb0[i + k] : n0;
            u1[k] = v1 ? cb1[i + k] : n0;
            w0[k] = v0 ? 1.0f : 0.0f;
            w1[k] = v1 ? 1.0f : 0.0f;
        }
        u16x8 m0[4], m1[4];
#pragma unroll
        for (int k = 0; k < 4; k++) m0[k] = G[(size_t)u0[k] * 16 + l16];
#pragma unroll
        for (int k = 0; k < 4; k++) m1[k] = G[(size_t)u1[k] * 16 + l16];
        if (DISU) {
#pragma unroll
            for (int k = 0; k < 4; k++) {
                w0[k] *= rsqrtf((float)(cnt[u0[k]] + 1));
                w1[k] *= rsqrtf((float)(cnt[u1[k]] + 1));
            }
        }
#pragma unroll
        for (int j = 0; j < 8; j++) {
            float a0 = fmaf(bf2f(m0[0][j]), w0[0], bf2f(m0[1][j]) * w0[1]);
            float b0 = fmaf(bf2f(m0[2][j]), w0[2], bf2f(m0[3][j]) * w0[3]);
            acc0[j] += a0 + b0;
            float a1 = fmaf(bf2f(m1[0][j]), w1[0], bf2f(m1[1][j]) * w1[1]);
            float b1v = fmaf(bf2f(m1[2][j]), w1[2], bf2f(m1[3][j]) * w1[3]);
            acc1[j] += a1 + b1v;
        }
    }
    for (; i < dm; i++) {
        if (i < d0) {
            int u = cb0[i];
            u16x8 m = G[(size_t)u * 16 + l16];
            float du = DISU ? rsqrtf((float)(cnt[u] + 1)) : 1.0f;
#pragma unroll
            for (int j = 0; j < 8; j++) acc0[j] += bf2f(m[j]) * du;
        }
        if (i < d1) {
            int u = cb1[i];
            u16x8 m = G[(size_t)u * 16 + l16];
            float du = DISU ? rsqrtf((float)(cnt[u] + 1)) : 1.0f;
#pragma unroll
            for (int j = 0; j < 8; j++) acc1[j] += bf2f(m[j]) * du;
        }
    }

    const float4* B4 = (const float4*)bias;
    float4 bb0 = B4[l16 * 2], bb1 = B4[l16 * 2 + 1];
#pragma unroll
    for (int nn = 0; nn < 2; nn++) {
        if (nn == 1 && !has1) break;
        int node = nn ? n1 : n0;
        float dv = nn ? dv1 : dv0;
        float* ac = nn ? acc1 : acc0;
        float r[8];
        r[0] = fmaf(ac[0], dv, bb0.x); r[1] = fmaf(ac[1], dv, bb0.y);
        r[2] = fmaf(ac[2], dv, bb0.z); r[3] = fmaf(ac[3], dv, bb0.w);
        r[4] = fmaf(ac[4], dv, bb1.x); r[5] = fmaf(ac[5], dv, bb1.y);
        r[6] = fmaf(ac[6], dv, bb1.z); r[7] = fmaf(ac[7], dv, bb1.w);
        if (RELU) {
#pragma unroll
            for (int j = 0; j < 8; j++) r[j] = fmaxf(r[j], 0.f);
        }
        if (OUT_BF16) {
            u16x8 o;
#pragma unroll
            for (int j = 0; j < 8; j++) o[j] = f2bf(r[j]);
            ((u16x8*)out)[(size_t)node * 16 + l16] = o;
        } else {
            float4 o0 = make_float4(r[0], r[1], r[2], r[3]);
            float4 o1 = make_float4(r[4], r[5], r[6], r[7]);
            ((float4*)out)[(size_t)node * 32 + l16 * 2]     = o0;
            ((float4*)out)[(size_t)node * 32 + l16 * 2 + 1] = o1;
        }
    }
}

// ---------- launch ----------

extern "C" void kernel_launch(void* const* d_in, const int* in_sizes, int n_in,
                              void* d_out, int out_size, void* d_ws, size_t ws_size,
                              hipStream_t stream) {
    const float* x  = (const float*)d_in[0];
    const int*   ei = (const int*)d_in[1];
    const float* W1 = (const float*)d_in[2];
    const float* b1 = (const float*)d_in[3];
    const float* W2 = (const float*)d_in[4];
    const float* b2 = (const float*)d_in[5];
    float* out = (float*)d_out;

    int N = in_sizes[0] / D;
    int E = in_sizes[1] / 2;
    int NBK = (N + 511) >> 9;                // buckets of 512 nodes

    // ws: g 25.6 | g2 25.6 | cnt .4 | rp .4 | col E*4=3.2 | Wb .13
    //   | bcnt ~1KB | gcnt | brec 4  -> ~59.4 MB
    char* w = (char*)d_ws;
    unsigned short* g  = (unsigned short*)w;  size_t off = (size_t)N * D * 2;
    off = (off + 255) & ~(size_t)255;
    unsigned short* g2 = (unsigned short*)(w + off); off += (size_t)N * D * 2;
    off = (off + 255) & ~(size_t)255;
    int* cnt  = (int*)(w + off);             off += (size_t)N * 4;
    off = (off + 255) & ~(size_t)255;
    int* rp   = (int*)(w + off);             off += (size_t)N * 4;
    off = (off + 255) & ~(size_t)255;
    int* col  = (int*)(w + off);             off += (size_t)E * 4;
    off = (off + 255) & ~(size_t)255;
    unsigned short* Wb1 = (unsigned short*)(w + off); off += (size_t)D * D * 2;
    unsigned short* Wb2 = (unsigned short*)(w + off); off += (size_t)D * D * 2;
    off = (off + 255) & ~(size_t)255;
    int* bcnt = (int*)(w + off);             off += (size_t)NBK * 4;
    off = (off + 255) & ~(size_t)255;
    int* gcnt = (int*)(w + off);             off += 256;
    unsigned* brec = (unsigned*)(w + off);   off += (size_t)NBK * SC * 4;
    // intermediate h (bf16 N*D = 25.6 MB) lives in d_out (free until agg2)
    unsigned short* h = (unsigned short*)d_out;

    int ntiles = (N + 127) / 128;
    int fillB  = (E + BE - 1) / BE;
    int fb = fillB > (ntiles + 3) / 4 ? fillB : (ntiles + 3) / 4;
    int total  = 5 * fb;
    int agg_grid = (N + 31) / 32;            // 2 nodes per 16-lane group

    k_prep<<<(D * D + 511) / 256, 256, 0, stream>>>(W1, W2, Wb1, Wb2, bcnt, gcnt, NBK);

    // K1: counting-sort (ei -> bcnt,brec)  ||  gemm1 (g = bf16(x @ W1^T), raw)
    k_sort_gemm1<<<total, 256, 0, stream>>>(ei, bcnt, brec, x, Wb1, g, N, E,
                                            ntiles, fillB, NBK);
    // build: brec -> dense CSR (col, rp, cnt)
    k_build<<<NBK, 256, 0, stream>>>(bcnt, brec, cnt, rp, col, gcnt, N);

    // agg1: h = bf16(relu(dis_v*(Σ dis_u g[u] + dis_v g[v]) + b1)) -> d_out
    k_agg<true, true, true><<<agg_grid, 256, 0, stream>>>(g, cnt, rp, col, b1, h, N);

    // gemm2: g2 = bf16((h @ W2^T) * dis)
    k_gemm2<<<ntiles, 256, 0, stream>>>(h, Wb2, cnt, g2, N, ntiles);

    // agg2: out = dis_v*(Σ g2[u] + g2[v]) + b2  (fp32) -> d_out
    k_agg<false, false, false><<<agg_grid, 256, 0, stream>>>(g2, cnt, rp, col, b2, out, N);
}

// Round 13
// 161.633 us; speedup vs baseline: 1.2856x; 1.0778x over previous
//
#include <hip/hip_runtime.h>

#define D 128
#define BE 4096     // edges per sort block
#define SC 5120     // brec records per bucket (Poisson(4096), 16-sigma headroom)

typedef __attribute__((ext_vector_type(8))) short bf16x8;
typedef __attribute__((ext_vector_type(4))) float f32x4;
typedef __attribute__((ext_vector_type(8))) unsigned short u16x8;

// ---------- bf16 helpers (manual, RNE) ----------
__device__ inline unsigned short f2bf(float f) {
    unsigned u = __float_as_uint(f);
    return (unsigned short)((u + 0x7fff + ((u >> 16) & 1)) >> 16);
}
__device__ inline float bf2f(unsigned short s) {
    return __uint_as_float((unsigned)s << 16);
}
__device__ inline bf16x8 cvt8(const float* __restrict__ p) {
    float4 a = *(const float4*)p;
    float4 b = *(const float4*)(p + 4);
    bf16x8 r;
    r[0] = (short)f2bf(a.x); r[1] = (short)f2bf(a.y);
    r[2] = (short)f2bf(a.z); r[3] = (short)f2bf(a.w);
    r[4] = (short)f2bf(b.x); r[5] = (short)f2bf(b.y);
    r[6] = (short)f2bf(b.z); r[7] = (short)f2bf(b.w);
    return r;
}

// ---------- prep: W1,W2 fp32 -> bf16; zero bucket counters + global base ---
__global__ void k_prep(const float* __restrict__ W1, const float* __restrict__ W2,
                       unsigned short* __restrict__ Wb1, unsigned short* __restrict__ Wb2,
                       int* __restrict__ bcnt, int* __restrict__ gcnt, int NBK) {
    int i = blockIdx.x * 256 + threadIdx.x;
    if (i < D * D) { Wb1[i] = f2bf(W1[i]); Wb2[i] = f2bf(W2[i]); }
    if (i < NBK) bcnt[i] = 0;
    if (i == D * D) *gcnt = 0;
}

// ---------- zero-LDS MFMA gemm tile (128 nodes per block, 32 per wave) -----
// C = W · x^T with mfma_f32_16x16x32_bf16; fragments straight from global.
// Per wave per ks: 16 rows x 128B(fp32)/64B(bf16) contiguous -> line-coalesced.
// C layout (m89): col(lane&15)=node, row=(lane>>4)*4+reg.
// #pragma unroll 1 on ks-loop: round-3 lesson (full unroll -> hoist/spill).

template <bool INBF16, bool FOLD>
__device__ inline void gemm_tile(const void* __restrict__ in_v,
                                 const unsigned short* __restrict__ Wb,
                                 const int* __restrict__ cnt,
                                 unsigned short* __restrict__ g,
                                 int N, int tile, int t) {
    int w = t >> 6, l = t & 63;
    int r16 = l & 15, g4 = l >> 4;
    int base = tile * 128 + w * 32;
    int row0 = base + r16, row1 = row0 + 16;
    int cr0 = (row0 < N) ? row0 : N - 1;
    int cr1 = (row1 < N) ? row1 : N - 1;

    f32x4 acc0[8] = {};
    f32x4 acc1[8] = {};
    const unsigned short* wr = Wb + r16 * D + g4 * 8;

#pragma unroll 1
    for (int ks = 0; ks < 4; ks++) {
        bf16x8 b0, b1;
        if (INBF16) {
            const unsigned short* h = (const unsigned short*)in_v;
            b0 = *(const bf16x8*)(h + (size_t)cr0 * D + g4 * 8 + ks * 32);
            b1 = *(const bf16x8*)(h + (size_t)cr1 * D + g4 * 8 + ks * 32);
        } else {
            const float* xx = (const float*)in_v;
            b0 = cvt8(xx + (size_t)cr0 * D + g4 * 8 + ks * 32);
            b1 = cvt8(xx + (size_t)cr1 * D + g4 * 8 + ks * 32);
        }
#pragma unroll
        for (int jt = 0; jt < 8; jt++) {
            bf16x8 a = *(const bf16x8*)(wr + jt * 16 * D + ks * 32);
            acc0[jt] = __builtin_amdgcn_mfma_f32_16x16x32_bf16(a, b0, acc0[jt], 0, 0, 0);
            acc1[jt] = __builtin_amdgcn_mfma_f32_16x16x32_bf16(a, b1, acc1[jt], 0, 0, 0);
        }
    }
#pragma unroll
    for (int tt = 0; tt < 2; tt++) {
        int row = base + tt * 16 + r16;
        if (row < N) {
            float dv = 1.0f;
            if (FOLD) dv = rsqrtf((float)(cnt[row] + 1));
#pragma unroll
            for (int jt = 0; jt < 8; jt++) {
                f32x4 a = tt ? acc1[jt] : acc0[jt];
                ushort4 o = { f2bf(a[0] * dv), f2bf(a[1] * dv),
                              f2bf(a[2] * dv), f2bf(a[3] * dv) };
                *(ushort4*)&g[(size_t)row * D + jt * 16 + g4 * 4] = o;
            }
        }
    }
}

// ---------- sort: 4096 edges/block -> LDS counting sort by bucket dst>>9 ---
// Reserve global ranges with <=196 atomics/block, stream records out in
// bucket order (coalesced runs). Record=(src<<9)|(dst&511); N < 2^17.
// NOTE: harness delivers integer inputs as int32 (edge_index arrives as int*).

__global__ __launch_bounds__(256) void k_sort(
        const int* __restrict__ ei, int* __restrict__ bcnt, unsigned* __restrict__ brec,
        int E, int NBK) {
    __shared__ unsigned srt[BE];            // 16 KB
    __shared__ unsigned char bko[BE];       // 4 KB
    __shared__ int hist[256];
    __shared__ int pfx[256];
    __shared__ int gbase[256];
    __shared__ int cur[256];
    int t = threadIdx.x;
    int e0 = blockIdx.x * BE;
    int n = E - e0; if (n > BE) n = BE;

    hist[t] = 0; cur[t] = 0;
    __syncthreads();

    unsigned rec[16]; int mb[16];
#pragma unroll
    for (int j = 0; j < 16; j++) {
        int e = e0 + j * 256 + t;           // coalesced
        if (e < E) {
            int s = ei[e], d = ei[E + e];
            rec[j] = ((unsigned)s << 9) | (unsigned)(d & 511);
            mb[j] = d >> 9;
            atomicAdd(&hist[mb[j]], 1);
        } else mb[j] = -1;
    }
    __syncthreads();
    int v = hist[t];
    pfx[t] = v;
    __syncthreads();
    for (int dd = 1; dd < 256; dd <<= 1) {
        int xv = (t >= dd) ? pfx[t - dd] : 0;
        __syncthreads();
        pfx[t] += xv;
        __syncthreads();
    }
    pfx[t] -= v;                            // exclusive prefix
    if (v > 0 && t < NBK) gbase[t] = atomicAdd(&bcnt[t], v);
    __syncthreads();
#pragma unroll
    for (int j = 0; j < 16; j++) {
        if (mb[j] >= 0) {
            int p = pfx[mb[j]] + atomicAdd(&cur[mb[j]], 1);
            srt[p] = rec[j];
            bko[p] = (unsigned char)mb[j];
        }
    }
    __syncthreads();
    for (int i = t; i < n; i += 256) {      // bucket-ordered -> coalesced
        int b = bko[i];
        int pos = gbase[b] + (i - pfx[b]);
        if (pos < SC) brec[(size_t)b * SC + pos] = srt[i];
    }
}

// ---------- fused: CSR build (1/5 of blocks) || gemm1 (4/5) ----------------
// Build and gemm1 are independent (build: brec->col,rp,cnt ; gemm1: x->g raw);
// agg1 is the join. Build's latency-bound LDS scan/scatter hides under
// gemm1's streaming (round-9 lesson: fusion is the only overlap tool, the
// stream serializes standalone kernels).

__global__ __launch_bounds__(256) void k_build_gemm1(
        const int* __restrict__ bcnt, const unsigned* __restrict__ brec,
        int* __restrict__ cnt, int* __restrict__ rp, int* __restrict__ col,
        int* __restrict__ gcnt,
        const float* __restrict__ x, const unsigned short* __restrict__ Wb1,
        unsigned short* __restrict__ g, int N, int ntiles, int NBK) {
    int bid = blockIdx.x;
    if (bid % 5 == 4) {                         // ---- build role ----
        __shared__ int c512[512];
        __shared__ int base512[512];
        __shared__ int psc[256];
        __shared__ int bksum;
        int b = bid / 5, t = threadIdx.x;
        if (b >= NBK) return;
        c512[t] = 0; c512[t + 256] = 0;
        __syncthreads();
        int total = bcnt[b]; if (total > SC) total = SC;
        for (int i = t; i < total; i += 256)
            atomicAdd(&c512[brec[(size_t)b * SC + i] & 511], 1);
        __syncthreads();
        int d0 = c512[2 * t], d1 = c512[2 * t + 1];
        int pair = d0 + d1;
        psc[t] = pair;
        __syncthreads();
        for (int dd = 1; dd < 256; dd <<= 1) {
            int xv = (t >= dd) ? psc[t - dd] : 0;
            __syncthreads();
            psc[t] += xv;
            __syncthreads();
        }
        int pexc = psc[t] - pair;
        if (t == 255) bksum = atomicAdd(gcnt, psc[255]);
        __syncthreads();
        int gb = bksum;
        base512[2 * t]     = gb + pexc;
        base512[2 * t + 1] = gb + pexc + d0;
        c512[2 * t] = 0; c512[2 * t + 1] = 0;
        __syncthreads();
        for (int i = t; i < total; i += 256) {
            unsigned rec = brec[(size_t)b * SC + i];
            int dl = rec & 511;
            int p = atomicAdd(&c512[dl], 1);
            col[base512[dl] + p] = (int)(rec >> 9);
        }
        __syncthreads();
#pragma unroll
        for (int k = 0; k < 2; k++) {
            int dl = t + k * 256;
            int node = b * 512 + dl;
            if (node < N) { cnt[node] = c512[dl]; rp[node] = base512[dl]; }
        }
    } else {                                    // ---- gemm1 role ----
        int gid = (bid / 5) * 4 + (bid % 5);
        if (gid >= ntiles) return;
        gemm_tile<false, false>(x, Wb1, nullptr, g, N, gid, threadIdx.x);
    }
}

// ---------- standalone gemm2 (bf16 in, dis-folded out) ----------
__global__ __launch_bounds__(256) void k_gemm2(
        const unsigned short* __restrict__ h, const unsigned short* __restrict__ Wb2,
        const int* __restrict__ cnt, unsigned short* __restrict__ g2, int N, int ntiles) {
    if ((int)blockIdx.x >= ntiles) return;
    gemm_tile<true, true>(h, Wb2, cnt, g2, N, blockIdx.x, threadIdx.x);
}

// ---------- sparse aggregation: round-10 proven shape ----------
// quarter-wave (16 lanes x u16x8 = 256B) per node, 4 gathers in flight,
// VGPR ~28 -> ~60% occupancy (round-12 lesson: 2-node variant raised VGPR
// to 48, occ 37%, and regressed — the agg is fabric-bound at high occ).
// DISU (layer 1): per-edge dis_u = rsqrt(cnt[u]+1) since g is raw.

template <bool RELU, bool OUT_BF16, bool DISU>
__global__ __launch_bounds__(256) void k_agg(
        const unsigned short* __restrict__ gtab, const int* __restrict__ cnt,
        const int* __restrict__ rp, const int* __restrict__ col,
        const float* __restrict__ bias, void* __restrict__ out, int N) {
    int node = blockIdx.x * 16 + (threadIdx.x >> 4);
    if (node >= N) return;
    int l16 = threadIdx.x & 15;
    const u16x8* G = (const u16x8*)gtab;    // 16 u16x8 per row
    int deg = cnt[node];
    float disv = rsqrtf((float)(deg + 1));
    float acc[8];
    {
        u16x8 s = G[(size_t)node * 16 + l16];   // self-loop term
        float sf = DISU ? disv : 1.0f;
#pragma unroll
        for (int j = 0; j < 8; j++) acc[j] = bf2f(s[j]) * sf;
    }
    const int* cb = col + rp[node];
    int i = 0;
    for (; i + 3 < deg; i += 4) {
        int u0 = cb[i], u1 = cb[i + 1], u2 = cb[i + 2], u3 = cb[i + 3];
        u16x8 m0 = G[(size_t)u0 * 16 + l16];
        u16x8 m1 = G[(size_t)u1 * 16 + l16];
        u16x8 m2 = G[(size_t)u2 * 16 + l16];
        u16x8 m3 = G[(size_t)u3 * 16 + l16];
        if (DISU) {
            float d0 = rsqrtf((float)(cnt[u0] + 1));
            float d1 = rsqrtf((float)(cnt[u1] + 1));
            float d2 = rsqrtf((float)(cnt[u2] + 1));
            float d3 = rsqrtf((float)(cnt[u3] + 1));
#pragma unroll
            for (int j = 0; j < 8; j++)
                acc[j] += (bf2f(m0[j]) * d0 + bf2f(m1[j]) * d1)
                        + (bf2f(m2[j]) * d2 + bf2f(m3[j]) * d3);
        } else {
#pragma unroll
            for (int j = 0; j < 8; j++)
                acc[j] += (bf2f(m0[j]) + bf2f(m1[j])) + (bf2f(m2[j]) + bf2f(m3[j]));
        }
    }
    for (; i < deg; i++) {
        int u = cb[i];
        u16x8 m = G[(size_t)u * 16 + l16];
        float du = DISU ? rsqrtf((float)(cnt[u] + 1)) : 1.0f;
#pragma unroll
        for (int j = 0; j < 8; j++) acc[j] += bf2f(m[j]) * du;
    }
    const float4* B4 = (const float4*)bias;
    float4 bb0 = B4[l16 * 2], bb1 = B4[l16 * 2 + 1];
    float r[8];
    r[0] = fmaf(acc[0], disv, bb0.x); r[1] = fmaf(acc[1], disv, bb0.y);
    r[2] = fmaf(acc[2], disv, bb0.z); r[3] = fmaf(acc[3], disv, bb0.w);
    r[4] = fmaf(acc[4], disv, bb1.x); r[5] = fmaf(acc[5], disv, bb1.y);
    r[6] = fmaf(acc[6], disv, bb1.z); r[7] = fmaf(acc[7], disv, bb1.w);
    if (RELU) {
#pragma unroll
        for (int j = 0; j < 8; j++) r[j] = fmaxf(r[j], 0.f);
    }
    if (OUT_BF16) {
        u16x8 o;
#pragma unroll
        for (int j = 0; j < 8; j++) o[j] = f2bf(r[j]);
        ((u16x8*)out)[(size_t)node * 16 + l16] = o;
    } else {
        float4 o0 = make_float4(r[0], r[1], r[2], r[3]);
        float4 o1 = make_float4(r[4], r[5], r[6], r[7]);
        ((float4*)out)[(size_t)node * 32 + l16 * 2]     = o0;
        ((float4*)out)[(size_t)node * 32 + l16 * 2 + 1] = o1;
    }
}

// ---------- launch ----------

extern "C" void kernel_launch(void* const* d_in, const int* in_sizes, int n_in,
                              void* d_out, int out_size, void* d_ws, size_t ws_size,
                              hipStream_t stream) {
    const float* x  = (const float*)d_in[0];
    const int*   ei = (const int*)d_in[1];
    const float* W1 = (const float*)d_in[2];
    const float* b1 = (const float*)d_in[3];
    const float* W2 = (const float*)d_in[4];
    const float* b2 = (const float*)d_in[5];
    float* out = (float*)d_out;

    int N = in_sizes[0] / D;
    int E = in_sizes[1] / 2;
    int NBK = (N + 511) >> 9;                // buckets of 512 nodes

    // ws: g 25.6 | g2 25.6 | cnt .4 | rp .4 | col E*4=3.2 | Wb .13
    //   | bcnt ~1KB | gcnt | brec 4  -> ~59.4 MB
    char* w = (char*)d_ws;
    unsigned short* g  = (unsigned short*)w;  size_t off = (size_t)N * D * 2;
    off = (off + 255) & ~(size_t)255;
    unsigned short* g2 = (unsigned short*)(w + off); off += (size_t)N * D * 2;
    off = (off + 255) & ~(size_t)255;
    int* cnt  = (int*)(w + off);             off += (size_t)N * 4;
    off = (off + 255) & ~(size_t)255;
    int* rp   = (int*)(w + off);             off += (size_t)N * 4;
    off = (off + 255) & ~(size_t)255;
    int* col  = (int*)(w + off);             off += (size_t)E * 4;
    off = (off + 255) & ~(size_t)255;
    unsigned short* Wb1 = (unsigned short*)(w + off); off += (size_t)D * D * 2;
    unsigned short* Wb2 = (unsigned short*)(w + off); off += (size_t)D * D * 2;
    off = (off + 255) & ~(size_t)255;
    int* bcnt = (int*)(w + off);             off += (size_t)NBK * 4;
    off = (off + 255) & ~(size_t)255;
    int* gcnt = (int*)(w + off);             off += 256;
    unsigned* brec = (unsigned*)(w + off);   off += (size_t)NBK * SC * 4;
    // intermediate h (bf16 N*D = 25.6 MB) lives in d_out (free until agg2)
    unsigned short* h = (unsigned short*)d_out;

    int ntiles = (N + 127) / 128;
    int sortB  = (E + BE - 1) / BE;          // 196 sort blocks
    int fb = NBK > (ntiles + 3) / 4 ? NBK : (ntiles + 3) / 4;
    int total  = 5 * fb;                     // 1 build : 4 gemm interleave
    int agg_grid = (N + 15) / 16;

    k_prep<<<(D * D + 511) / 256, 256, 0, stream>>>(W1, W2, Wb1, Wb2, bcnt, gcnt, NBK);

    // sort: ei -> bcnt, brec (all coalesced)
    k_sort<<<sortB, 256, 0, stream>>>(ei, bcnt, brec, E, NBK);

    // fused: build (brec -> col,rp,cnt)  ||  gemm1 (g = bf16(x @ W1^T), raw)
    k_build_gemm1<<<total, 256, 0, stream>>>(bcnt, brec, cnt, rp, col, gcnt,
                                             x, Wb1, g, N, ntiles, NBK);

    // agg1: h = bf16(relu(dis_v*(Σ dis_u g[u] + dis_v g[v]) + b1)) -> d_out
    k_agg<true, true, true><<<agg_grid, 256, 0, stream>>>(g, cnt, rp, col, b1, h, N);

    // gemm2: g2 = bf16((h @ W2^T) * dis)
    k_gemm2<<<ntiles, 256, 0, stream>>>(h, Wb2, cnt, g2, N, ntiles);

    // agg2: out = dis_v*(Σ g2[u] + g2[v]) + b2  (fp32) -> d_out
    k_agg<false, false, false><<<agg_grid, 256, 0, stream>>>(g2, cnt, rp, col, b2, out, N);
}

// Round 14
// 160.034 us; speedup vs baseline: 1.2985x; 1.0100x over previous
//
#include <hip/hip_runtime.h>

#define D 128
#define BE 4096     // edges per sort block
#define SC 5120     // brec records per bucket (Poisson(4096), 16-sigma headroom)
#define LROW 136    // padded LDS row stride in ushorts (272 B -> 2-way banks, free)

typedef __attribute__((ext_vector_type(8))) short bf16x8;
typedef __attribute__((ext_vector_type(4))) float f32x4;
typedef __attribute__((ext_vector_type(8))) unsigned short u16x8;

// ---------- bf16 helpers (manual, RNE) ----------
__device__ inline unsigned short f2bf(float f) {
    unsigned u = __float_as_uint(f);
    return (unsigned short)((u + 0x7fff + ((u >> 16) & 1)) >> 16);
}
__device__ inline float bf2f(unsigned short s) {
    return __uint_as_float((unsigned)s << 16);
}
__device__ inline bf16x8 cvt8(const float* __restrict__ p) {
    float4 a = *(const float4*)p;
    float4 b = *(const float4*)(p + 4);
    bf16x8 r;
    r[0] = (short)f2bf(a.x); r[1] = (short)f2bf(a.y);
    r[2] = (short)f2bf(a.z); r[3] = (short)f2bf(a.w);
    r[4] = (short)f2bf(b.x); r[5] = (short)f2bf(b.y);
    r[6] = (short)f2bf(b.z); r[7] = (short)f2bf(b.w);
    return r;
}

// ---------- prep: W1,W2 fp32 -> bf16; zero bucket counters + global base ---
__global__ void k_prep(const float* __restrict__ W1, const float* __restrict__ W2,
                       unsigned short* __restrict__ Wb1, unsigned short* __restrict__ Wb2,
                       int* __restrict__ bcnt, int* __restrict__ gcnt, int NBK) {
    int i = blockIdx.x * 256 + threadIdx.x;
    if (i < D * D) { Wb1[i] = f2bf(W1[i]); Wb2[i] = f2bf(W2[i]); }
    if (i < NBK) bcnt[i] = 0;
    if (i == D * D) *gcnt = 0;
}

// ---------- zero-LDS MFMA gemm tile (128 nodes per block, 32 per wave) -----
// C = W · x^T with mfma_f32_16x16x32_bf16; fragments straight from global.
// C layout (m89): col(lane&15)=node, row=(lane>>4)*4+reg.
// #pragma unroll 1 on ks-loop: round-3 lesson (full unroll -> hoist/spill).

__device__ inline void gemm1_tile(const float* __restrict__ xx,
                                  const unsigned short* __restrict__ Wb,
                                  unsigned short* __restrict__ g,
                                  int N, int tile, int t) {
    int w = t >> 6, l = t & 63;
    int r16 = l & 15, g4 = l >> 4;
    int base = tile * 128 + w * 32;
    int row0 = base + r16, row1 = row0 + 16;
    int cr0 = (row0 < N) ? row0 : N - 1;
    int cr1 = (row1 < N) ? row1 : N - 1;

    f32x4 acc0[8] = {};
    f32x4 acc1[8] = {};
    const unsigned short* wr = Wb + r16 * D + g4 * 8;

#pragma unroll 1
    for (int ks = 0; ks < 4; ks++) {
        bf16x8 b0 = cvt8(xx + (size_t)cr0 * D + g4 * 8 + ks * 32);
        bf16x8 b1 = cvt8(xx + (size_t)cr1 * D + g4 * 8 + ks * 32);
#pragma unroll
        for (int jt = 0; jt < 8; jt++) {
            bf16x8 a = *(const bf16x8*)(wr + jt * 16 * D + ks * 32);
            acc0[jt] = __builtin_amdgcn_mfma_f32_16x16x32_bf16(a, b0, acc0[jt], 0, 0, 0);
            acc1[jt] = __builtin_amdgcn_mfma_f32_16x16x32_bf16(a, b1, acc1[jt], 0, 0, 0);
        }
    }
#pragma unroll
    for (int tt = 0; tt < 2; tt++) {
        int row = base + tt * 16 + r16;
        if (row < N) {
#pragma unroll
            for (int jt = 0; jt < 8; jt++) {
                f32x4 a = tt ? acc1[jt] : acc0[jt];
                ushort4 o = { f2bf(a[0]), f2bf(a[1]), f2bf(a[2]), f2bf(a[3]) };
                *(ushort4*)&g[(size_t)row * D + jt * 16 + g4 * 4] = o;
            }
        }
    }
}

// ---------- K1: edge counting-sort (1/3) || gemm1 tiles [0,ntA) (2/3) ------
// Sort: 4096 edges -> LDS counting sort by bucket dst>>9, reserve global
// ranges with <=NBK atomics, stream out coalesced. Record=(src<<9)|(dst&511).
// NOTE: harness delivers integer inputs as int32 (edge_index arrives as int*).

__global__ __launch_bounds__(256) void k_sort_gemm1a(
        const int* __restrict__ ei, int* __restrict__ bcnt, unsigned* __restrict__ brec,
        const float* __restrict__ x, const unsigned short* __restrict__ Wb1,
        unsigned short* __restrict__ g, int N, int E, int ntA, int sortB, int NBK) {
    int bid = blockIdx.x;
    if (bid % 3 == 2) {                         // ---- sort role ----
        __shared__ unsigned srt[BE];            // 16 KB
        __shared__ unsigned char bko[BE];       // 4 KB
        __shared__ int hist[256];
        __shared__ int pfx[256];
        __shared__ int gbase[256];
        __shared__ int cur[256];
        int f = bid / 3;
        if (f >= sortB) return;
        int t = threadIdx.x;
        int e0 = f * BE;
        int n = E - e0; if (n > BE) n = BE;
        hist[t] = 0; cur[t] = 0;
        __syncthreads();
        unsigned rec[16]; int mb[16];
#pragma unroll
        for (int j = 0; j < 16; j++) {
            int e = e0 + j * 256 + t;           // coalesced
            if (e < E) {
                int s = ei[e], d = ei[E + e];
                rec[j] = ((unsigned)s << 9) | (unsigned)(d & 511);
                mb[j] = d >> 9;
                atomicAdd(&hist[mb[j]], 1);
            } else mb[j] = -1;
        }
        __syncthreads();
        int v = hist[t];
        pfx[t] = v;
        __syncthreads();
        for (int dd = 1; dd < 256; dd <<= 1) {
            int xv = (t >= dd) ? pfx[t - dd] : 0;
            __syncthreads();
            pfx[t] += xv;
            __syncthreads();
        }
        pfx[t] -= v;                            // exclusive prefix
        if (v > 0 && t < NBK) gbase[t] = atomicAdd(&bcnt[t], v);
        __syncthreads();
#pragma unroll
        for (int j = 0; j < 16; j++) {
            if (mb[j] >= 0) {
                int p = pfx[mb[j]] + atomicAdd(&cur[mb[j]], 1);
                srt[p] = rec[j];
                bko[p] = (unsigned char)mb[j];
            }
        }
        __syncthreads();
        for (int i = t; i < n; i += 256) {      // bucket-ordered -> coalesced
            int b = bko[i];
            int pos = gbase[b] + (i - pfx[b]);
            if (pos < SC) brec[(size_t)b * SC + pos] = srt[i];
        }
    } else {                                    // ---- gemm1 role ----
        int gid = (bid / 3) * 2 + (bid % 3);
        if (gid >= ntA) return;
        gemm1_tile(x, Wb1, g, N, gid, threadIdx.x);
    }
}

// ---------- K2: CSR build (1/3) || gemm1 tiles [ntA,ntiles) (2/3) ----------
__global__ __launch_bounds__(256) void k_build_gemm1b(
        const int* __restrict__ bcnt, const unsigned* __restrict__ brec,
        int* __restrict__ cnt, int* __restrict__ rp, int* __restrict__ col,
        int* __restrict__ gcnt,
        const float* __restrict__ x, const unsigned short* __restrict__ Wb1,
        unsigned short* __restrict__ g, int N, int ntA, int ntiles, int NBK) {
    int bid = blockIdx.x;
    if (bid % 3 == 2) {                         // ---- build role ----
        __shared__ int c512[512];
        __shared__ int base512[512];
        __shared__ int psc[256];
        __shared__ int bksum;
        int b = bid / 3, t = threadIdx.x;
        if (b >= NBK) return;
        c512[t] = 0; c512[t + 256] = 0;
        __syncthreads();
        int total = bcnt[b]; if (total > SC) total = SC;
        for (int i = t; i < total; i += 256)
            atomicAdd(&c512[brec[(size_t)b * SC + i] & 511], 1);
        __syncthreads();
        int d0 = c512[2 * t], d1 = c512[2 * t + 1];
        int pair = d0 + d1;
        psc[t] = pair;
        __syncthreads();
        for (int dd = 1; dd < 256; dd <<= 1) {
            int xv = (t >= dd) ? psc[t - dd] : 0;
            __syncthreads();
            psc[t] += xv;
            __syncthreads();
        }
        int pexc = psc[t] - pair;
        if (t == 255) bksum = atomicAdd(gcnt, psc[255]);
        __syncthreads();
        int gb = bksum;
        base512[2 * t]     = gb + pexc;
        base512[2 * t + 1] = gb + pexc + d0;
        c512[2 * t] = 0; c512[2 * t + 1] = 0;
        __syncthreads();
        for (int i = t; i < total; i += 256) {
            unsigned rec = brec[(size_t)b * SC + i];
            int dl = rec & 511;
            int p = atomicAdd(&c512[dl], 1);
            col[base512[dl] + p] = (int)(rec >> 9);
        }
        __syncthreads();
#pragma unroll
        for (int k = 0; k < 2; k++) {
            int dl = t + k * 256;
            int node = b * 512 + dl;
            if (node < N) { cnt[node] = c512[dl]; rp[node] = base512[dl]; }
        }
    } else {                                    // ---- gemm1 role ----
        int gid = ntA + (bid / 3) * 2 + (bid % 3);
        if (gid >= ntiles) return;
        gemm1_tile(x, Wb1, g, N, gid, threadIdx.x);
    }
}

// ---------- fused agg1 + row-local gemm2 ----------
// Agg phase: EXACT r13 shape (16-lane group per node, 4 gathers deep, full
// concurrency — round-11 lesson respected). h goes to a 4.3 KB LDS tile
// (16 nodes = one MFMA B-frag column set), never to HBM. One barrier, then
// each wave does 2jt x 4ks MFMAs with W2 A-frags (L2-hot) and writes g2
// dis-folded. Saves the 51 MB h round-trip + the gemm2 launch; numerics
// identical (h rounds through bf16 either way).

__global__ __launch_bounds__(256) void k_agg1_g2(
        const unsigned short* __restrict__ gtab, const int* __restrict__ cnt,
        const int* __restrict__ rp, const int* __restrict__ col,
        const float* __restrict__ b1, const unsigned short* __restrict__ Wb2,
        unsigned short* __restrict__ g2, int N) {
    __shared__ __align__(16) unsigned short hl[16 * LROW];   // 4.3 KB
    int t = threadIdx.x, grp = t >> 4, l16 = t & 15;
    int n0 = blockIdx.x * 16;
    int node = n0 + grp;
    bool valid = (node < N);
    int nc = valid ? node : N - 1;
    const u16x8* G = (const u16x8*)gtab;

    int deg = valid ? cnt[node] : 0;
    float disv = rsqrtf((float)(deg + 1));
    float acc[8];
    {
        u16x8 s = G[(size_t)nc * 16 + l16];     // self-loop term (x dis_v)
#pragma unroll
        for (int j = 0; j < 8; j++) acc[j] = bf2f(s[j]) * disv;
    }
    const int* cb = col + (valid ? rp[node] : 0);
    int i = 0;
    for (; i + 3 < deg; i += 4) {
        int u0 = cb[i], u1 = cb[i + 1], u2 = cb[i + 2], u3 = cb[i + 3];
        u16x8 m0 = G[(size_t)u0 * 16 + l16];
        u16x8 m1 = G[(size_t)u1 * 16 + l16];
        u16x8 m2 = G[(size_t)u2 * 16 + l16];
        u16x8 m3 = G[(size_t)u3 * 16 + l16];
        float d0 = rsqrtf((float)(cnt[u0] + 1));
        float d1 = rsqrtf((float)(cnt[u1] + 1));
        float d2 = rsqrtf((float)(cnt[u2] + 1));
        float d3 = rsqrtf((float)(cnt[u3] + 1));
#pragma unroll
        for (int j = 0; j < 8; j++)
            acc[j] += (bf2f(m0[j]) * d0 + bf2f(m1[j]) * d1)
                    + (bf2f(m2[j]) * d2 + bf2f(m3[j]) * d3);
    }
    for (; i < deg; i++) {
        int u = cb[i];
        u16x8 m = G[(size_t)u * 16 + l16];
        float du = rsqrtf((float)(cnt[u] + 1));
#pragma unroll
        for (int j = 0; j < 8; j++) acc[j] += bf2f(m[j]) * du;
    }
    {
        const float4* B4 = (const float4*)b1;
        float4 bb0 = B4[l16 * 2], bb1 = B4[l16 * 2 + 1];
        float r[8];
        r[0] = fmaf(acc[0], disv, bb0.x); r[1] = fmaf(acc[1], disv, bb0.y);
        r[2] = fmaf(acc[2], disv, bb0.z); r[3] = fmaf(acc[3], disv, bb0.w);
        r[4] = fmaf(acc[4], disv, bb1.x); r[5] = fmaf(acc[5], disv, bb1.y);
        r[6] = fmaf(acc[6], disv, bb1.z); r[7] = fmaf(acc[7], disv, bb1.w);
        u16x8 hv;
#pragma unroll
        for (int j = 0; j < 8; j++)
            hv[j] = valid ? f2bf(fmaxf(r[j], 0.f)) : (unsigned short)0;
        *(u16x8*)&hl[grp * LROW + l16 * 8] = hv;
    }
    __syncthreads();

    // ---- mini-gemm2: B-frags = LDS h rows (node = lane&15), A = W2 ----
    int w = t >> 6, l = t & 63;
    int r16 = l & 15, g4 = l >> 4;
    f32x4 a0 = {}, a1 = {};
    const unsigned short* wr = Wb2 + r16 * D + g4 * 8;
    int xb = r16 * LROW + g4 * 8;
#pragma unroll 1
    for (int ks = 0; ks < 4; ks++) {
        bf16x8 b = *(const bf16x8*)&hl[xb + ks * 32];
        bf16x8 A0 = *(const bf16x8*)(wr + (2 * w) * 16 * D + ks * 32);
        bf16x8 A1 = *(const bf16x8*)(wr + (2 * w + 1) * 16 * D + ks * 32);
        a0 = __builtin_amdgcn_mfma_f32_16x16x32_bf16(A0, b, a0, 0, 0, 0);
        a1 = __builtin_amdgcn_mfma_f32_16x16x32_bf16(A1, b, a1, 0, 0, 0);
    }
    int orow = n0 + r16;
    if (orow < N) {
        float dv = rsqrtf((float)(cnt[orow] + 1));
        ushort4 o0 = { f2bf(a0[0] * dv), f2bf(a0[1] * dv),
                       f2bf(a0[2] * dv), f2bf(a0[3] * dv) };
        ushort4 o1 = { f2bf(a1[0] * dv), f2bf(a1[1] * dv),
                       f2bf(a1[2] * dv), f2bf(a1[3] * dv) };
        *(ushort4*)&g2[(size_t)orow * D + (2 * w) * 16 + g4 * 4] = o0;
        *(ushort4*)&g2[(size_t)orow * D + (2 * w + 1) * 16 + g4 * 4] = o1;
    }
}

// ---------- agg2: final aggregation -> fp32 out (r13 proven shape) ---------
__global__ __launch_bounds__(256) void k_agg2(
        const unsigned short* __restrict__ g2, const int* __restrict__ cnt,
        const int* __restrict__ rp, const int* __restrict__ col,
        const float* __restrict__ b2, float* __restrict__ out, int N) {
    int node = blockIdx.x * 16 + (threadIdx.x >> 4);
    if (node >= N) return;
    int l16 = threadIdx.x & 15;
    const u16x8* G = (const u16x8*)g2;
    int deg = cnt[node];
    float acc[8];
    {
        u16x8 s = G[(size_t)node * 16 + l16];
#pragma unroll
        for (int j = 0; j < 8; j++) acc[j] = bf2f(s[j]);
    }
    const int* cb = col + rp[node];
    int i = 0;
    for (; i + 3 < deg; i += 4) {
        int u0 = cb[i], u1 = cb[i + 1], u2 = cb[i + 2], u3 = cb[i + 3];
        u16x8 m0 = G[(size_t)u0 * 16 + l16];
        u16x8 m1 = G[(size_t)u1 * 16 + l16];
        u16x8 m2 = G[(size_t)u2 * 16 + l16];
        u16x8 m3 = G[(size_t)u3 * 16 + l16];
#pragma unroll
        for (int j = 0; j < 8; j++)
            acc[j] += (bf2f(m0[j]) + bf2f(m1[j])) + (bf2f(m2[j]) + bf2f(m3[j]));
    }
    for (; i < deg; i++) {
        u16x8 m = G[(size_t)cb[i] * 16 + l16];
#pragma unroll
        for (int j = 0; j < 8; j++) acc[j] += bf2f(m[j]);
    }
    float disv = rsqrtf((float)(deg + 1));
    const float4* B4 = (const float4*)b2;
    float4 bb0 = B4[l16 * 2], bb1 = B4[l16 * 2 + 1];
    float4 o0, o1;
    o0.x = fmaf(acc[0], disv, bb0.x); o0.y = fmaf(acc[1], disv, bb0.y);
    o0.z = fmaf(acc[2], disv, bb0.z); o0.w = fmaf(acc[3], disv, bb0.w);
    o1.x = fmaf(acc[4], disv, bb1.x); o1.y = fmaf(acc[5], disv, bb1.y);
    o1.z = fmaf(acc[6], disv, bb1.z); o1.w = fmaf(acc[7], disv, bb1.w);
    ((float4*)out)[(size_t)node * 32 + l16 * 2]     = o0;
    ((float4*)out)[(size_t)node * 32 + l16 * 2 + 1] = o1;
}

// ---------- launch ----------

extern "C" void kernel_launch(void* const* d_in, const int* in_sizes, int n_in,
                              void* d_out, int out_size, void* d_ws, size_t ws_size,
                              hipStream_t stream) {
    const float* x  = (const float*)d_in[0];
    const int*   ei = (const int*)d_in[1];
    const float* W1 = (const float*)d_in[2];
    const float* b1 = (const float*)d_in[3];
    const float* W2 = (const float*)d_in[4];
    const float* b2 = (const float*)d_in[5];
    float* out = (float*)d_out;

    int N = in_sizes[0] / D;
    int E = in_sizes[1] / 2;
    int NBK = (N + 511) >> 9;                // buckets of 512 nodes

    // ws: g 25.6 | g2 25.6 | cnt .4 | rp .4 | col E*4=3.2 | Wb .13
    //   | bcnt ~1KB | gcnt | brec 4  -> ~59.4 MB
    char* w = (char*)d_ws;
    unsigned short* g  = (unsigned short*)w;  size_t off = (size_t)N * D * 2;
    off = (off + 255) & ~(size_t)255;
    unsigned short* g2 = (unsigned short*)(w + off); off += (size_t)N * D * 2;
    off = (off + 255) & ~(size_t)255;
    int* cnt  = (int*)(w + off);             off += (size_t)N * 4;
    off = (off + 255) & ~(size_t)255;
    int* rp   = (int*)(w + off);             off += (size_t)N * 4;
    off = (off + 255) & ~(size_t)255;
    int* col  = (int*)(w + off);             off += (size_t)E * 4;
    off = (off + 255) & ~(size_t)255;
    unsigned short* Wb1 = (unsigned short*)(w + off); off += (size_t)D * D * 2;
    unsigned short* Wb2 = (unsigned short*)(w + off); off += (size_t)D * D * 2;
    off = (off + 255) & ~(size_t)255;
    int* bcnt = (int*)(w + off);             off += (size_t)NBK * 4;
    off = (off + 255) & ~(size_t)255;
    int* gcnt = (int*)(w + off);             off += 256;
    unsigned* brec = (unsigned*)(w + off);   off += (size_t)NBK * SC * 4;

    int ntiles = (N + 127) / 128;
    int ntA = (ntiles + 1) / 2;              // gemm1 tiles in K1
    int ntB = ntiles - ntA;                  // gemm1 tiles in K2
    int sortB = (E + BE - 1) / BE;
    int fb1 = sortB > (ntA + 1) / 2 ? sortB : (ntA + 1) / 2;
    int fb2 = NBK   > (ntB + 1) / 2 ? NBK   : (ntB + 1) / 2;
    int agg_grid = (N + 15) / 16;

    k_prep<<<(D * D + 511) / 256, 256, 0, stream>>>(W1, W2, Wb1, Wb2, bcnt, gcnt, NBK);

    // K1: sort (ei -> bcnt,brec)  ||  gemm1 tiles [0,ntA)
    k_sort_gemm1a<<<3 * fb1, 256, 0, stream>>>(ei, bcnt, brec, x, Wb1, g,
                                               N, E, ntA, sortB, NBK);
    // K2: build (brec -> col,rp,cnt)  ||  gemm1 tiles [ntA,ntiles)
    k_build_gemm1b<<<3 * fb2, 256, 0, stream>>>(bcnt, brec, cnt, rp, col, gcnt,
                                                x, Wb1, g, N, ntA, ntiles, NBK);

    // agg1 (+ row-local gemm2): g2 = bf16(dis*(relu(agg1)+b1... ) @ W2^T)
    k_agg1_g2<<<agg_grid, 256, 0, stream>>>(g, cnt, rp, col, b1, Wb2, g2, N);

    // agg2: out = dis_v*(Σ g2[u] + g2[v]) + b2  (fp32) -> d_out
    k_agg2<<<agg_grid, 256, 0, stream>>>(g2, cnt, rp, col, b2, out, N);
}